// Round 7
// baseline (39.404 us; speedup 1.0000x reference)
//
#include <hip/hip_runtime.h>
#include <hip/hip_bf16.h>

#define NEGC (-1e8f)

__device__ __forceinline__ float lrelu(float x) { return x >= 0.f ? x : 0.2f * x; }

// Shared edge-logit computation. MUST be bit-identical between the stats pass
// and the output pass: the neg-mask multiplies e by -1e8, so a 1-ulp
// difference becomes ~±50 in the logit and exp() explodes. Add/mul only (no
// fma-contraction ambiguity), fixed association e = ss + soj, with
// soj = s_other[j] + b_att computed identically in both kernels from the
// SAME stored s_other bits.
__device__ __forceinline__ void edge_pq(float ss, float soj, bool same,
                                        float& p, float& q) {
    float e = ss + soj;
    float pin = same ? e : e * NEGC;
    float nin = same ? e * NEGC : e;
    p = lrelu(pin);
    q = lrelu(nin);
}

// ---------------- Kernel A: 128 blocks x 512 thr. Block b owns rows/cols
// [8b, 8b+8). Redundantly computes u1/u2/c1/c2 and ALL s_self — but with a
// COALESCED cooperative sweep (16 groups x 32 lanes; one 512B row read per
// group per iteration; u2 fragment in registers; shfl reduce). Deterministic,
// so every block produces bit-identical values. Then column softmax stats for
// its 8 columns. Writes its s_self/s_other slice + stats.
__global__ __launch_bounds__(512) void kA_scores_stats(
        const float* __restrict__ node, const int* __restrict__ group,
        const float* __restrict__ W_emb, const float* __restrict__ b_emb,
        const float* __restrict__ w_att, const float* __restrict__ b_att,
        float* __restrict__ s_other_g, float* __restrict__ s_self_g,
        float* __restrict__ cmp_g, float* __restrict__ icsp_g,
        float* __restrict__ cmn_g, float* __restrict__ icsn_g) {
    int t = threadIdx.x;
    int b = blockIdx.x;
    int wv = t >> 6, lane = t & 63;

    __shared__ float part[1024];
    __shared__ float u1[128], u2[128];
    __shared__ float sself[1024];
    __shared__ int   grp[1024];
    __shared__ float cc[2];
    __shared__ float sothr[8];

    // group to LDS (coalesced)
    grp[t] = group[t];
    grp[t + 512] = group[t + 512];

    // --- u1/u2 partials: quarter q of the e-range, column k
    {
        int k = t & 127, q = t >> 7;
        float p1 = 0.f, p2 = 0.f;
        for (int e = 32 * q; e < 32 * q + 32; ++e) {
            float w = W_emb[e * 128 + k];
            p1 += w * w_att[e];
            p2 += w * w_att[128 + e];
        }
        part[q * 256 + k] = p1;
        part[q * 256 + 128 + k] = p2;
    }
    __syncthreads();
    if (t < 128) {
        u1[t] = part[t] + part[256 + t] + part[512 + t] + part[768 + t];
    } else if (t < 256) {
        int k = t - 128;
        u2[k] = part[128 + k] + part[384 + k] + part[640 + k] + part[896 + k];
    } else if (t < 320) {              // c1 = dot(b_emb, w_att[:128])
        int l = t - 256;
        float c = b_emb[l] * w_att[l] + b_emb[64 + l] * w_att[64 + l];
        for (int off = 32; off > 0; off >>= 1) c += __shfl_xor(c, off, 64);
        if (l == 0) cc[0] = c;
    } else if (t < 384) {              // c2 = dot(b_emb, w_att[128:])
        int l = t - 320;
        float c = b_emb[l] * w_att[128 + l] + b_emb[64 + l] * w_att[192 + l];
        for (int off = 32; off > 0; off >>= 1) c += __shfl_xor(c, off, 64);
        if (l == 0) cc[1] = c;
    }
    __syncthreads();

    // --- s_self for ALL rows, coalesced cooperative: group g32 (32 lanes)
    // handles row it*16+g32; lane l32 reads float4 at 16B*l32 (512B row).
    {
        int g32 = t >> 5, l32 = t & 31;
        float4 uv = ((const float4*)u2)[l32];   // register-resident u2 slice
        float c2 = cc[1];
#pragma unroll 4
        for (int it = 0; it < 64; ++it) {
            int row = it * 16 + g32;
            float4 x = ((const float4*)(node + (size_t)row * 128))[l32];
            float d = x.x * uv.x + x.y * uv.y + x.z * uv.z + x.w * uv.w;
#pragma unroll
            for (int off = 16; off > 0; off >>= 1) d += __shfl_xor(d, off, 64);
            if (l32 == 0) sself[row] = d + c2;
        }
    }

    // --- s_other for the block's 8 columns: wave wv -> col 8b+wv
    {
        int j = b * 8 + wv;
        const float2* row2 = (const float2*)(node + (size_t)j * 128);
        const float2* u12 = (const float2*)u1;
        float2 x = row2[lane], v = u12[lane];
        float d = x.x * v.x + x.y * v.y;
        for (int off = 32; off > 0; off >>= 1) d += __shfl_xor(d, off, 64);
        if (lane == 0) {
            float so = d + cc[0];
            sothr[wv] = so;
            s_other_g[j] = so;       // same bits K_B will load
        }
    }
    __syncthreads();

    if (t < 8) s_self_g[b * 8 + t] = sself[b * 8 + t];  // block's row slice

    // --- column stats: wave wv -> col j = 8b+wv
    float ba = b_att[0];
    float soj = sothr[wv] + ba;      // identical association to K_B
    int gj = grp[b * 8 + wv];
    float pv[16], nv[16];
    float pmax = -3.4e38f, nmax = -3.4e38f;
#pragma unroll
    for (int k = 0; k < 16; ++k) {
        int i = lane + k * 64;
        float p, q;
        edge_pq(sself[i], soj, grp[i] == gj, p, q);
        pv[k] = p; nv[k] = q;
        pmax = fmaxf(pmax, p);
        nmax = fmaxf(nmax, q);
    }
#pragma unroll
    for (int off = 32; off > 0; off >>= 1) {
        pmax = fmaxf(pmax, __shfl_xor(pmax, off, 64));
        nmax = fmaxf(nmax, __shfl_xor(nmax, off, 64));
    }
    float ps = 0.f, ns = 0.f;
#pragma unroll
    for (int k = 0; k < 16; ++k) {
        ps += __expf(pv[k] - pmax);
        ns += __expf(nv[k] - nmax);
    }
#pragma unroll
    for (int off = 32; off > 0; off >>= 1) {
        ps += __shfl_xor(ps, off, 64);
        ns += __shfl_xor(ns, off, 64);
    }
    if (lane == 0) {
        int j = b * 8 + wv;
        cmp_g[j] = pmax; icsp_g[j] = 1.f / ps;
        cmn_g[j] = nmax; icsn_g[j] = 1.f / ns;
    }
}

// ---------------- Kernel B: out[i,:] = sum_j A[i,j] * relu(node[j,:])
// BI=4 rows/block, 256 blocks x 512 thr. A rows filled once in 16 KB LDS;
// 16 j-groups of 32 lanes: 64-iter main loop, unroll 8. 32 KB LDS reused
// for the cross-group reduce. (Proven structure from R4.)
#define BI 4
__global__ __launch_bounds__(512) void kB_out(
        const float* __restrict__ node,
        const float* __restrict__ s_self,
        const float* __restrict__ s_other,
        const int* __restrict__ group,
        const float* __restrict__ b_att,
        const float* __restrict__ cmp, const float* __restrict__ icsp,
        const float* __restrict__ cmn, const float* __restrict__ icsn,
        float* __restrict__ out) {
    int t = threadIdx.x;       // 0..511
    int i0 = blockIdx.x * BI;

    __shared__ float buf[8192];   // 32 KB; first 4096 floats = sA[4][1024]
    __shared__ float ss_l[BI];
    __shared__ int   g_l[BI];
    if (t < BI) { ss_l[t] = s_self[i0 + t]; g_l[t] = group[i0 + t]; }
    __syncthreads();

    float ba = b_att[0];
#pragma unroll
    for (int e = 0; e < 8; ++e) {
        int idx = t + e * 512;        // 0..4095
        int r = idx >> 10;            // row 0..3
        int j = idx & 1023;
        float soj = s_other[j] + ba;  // identical association to kA
        float p, q;
        edge_pq(ss_l[r], soj, group[j] == g_l[r], p, q);
        buf[r * 1024 + j] = __expf(p - cmp[j]) * icsp[j]
                          + __expf(q - cmn[j]) * icsn[j];
    }
    __syncthreads();

    int lane = t & 31;   // float4 index within a 128-d row
    int g = t >> 5;      // j-group 0..15
    const float4* nf4 = (const float4*)node;

    float4 acc[BI];
#pragma unroll
    for (int r = 0; r < BI; ++r) acc[r] = make_float4(0.f, 0.f, 0.f, 0.f);

#pragma unroll 8
    for (int j = g; j < 1024; j += 16) {
        float4 x = nf4[(size_t)j * 32 + lane];
        float4 rn;
        rn.x = fmaxf(x.x, 0.f); rn.y = fmaxf(x.y, 0.f);
        rn.z = fmaxf(x.z, 0.f); rn.w = fmaxf(x.w, 0.f);
#pragma unroll
        for (int r = 0; r < BI; ++r) {
            float a = buf[r * 1024 + j];
            acc[r].x += a * rn.x; acc[r].y += a * rn.y;
            acc[r].z += a * rn.z; acc[r].w += a * rn.w;
        }
    }

    __syncthreads();  // done reading sA; reuse buf as reduce buffer
    float4* red = (float4*)buf;   // red[g*128 + r*32 + lane], 2048 float4
#pragma unroll
    for (int r = 0; r < BI; ++r) red[g * 128 + r * 32 + lane] = acc[r];
    __syncthreads();

    // 512 outputs (BI rows x 128 d); 1 per thread, contiguous store
    int r = t >> 7;
    int d = t & 127;
    float sum = 0.f;
#pragma unroll
    for (int gg = 0; gg < 16; ++gg)
        sum += buf[gg * 512 + r * 128 + d];
    out[(size_t)(i0 + r) * 128 + d] = sum;
}

extern "C" void kernel_launch(void* const* d_in, const int* in_sizes, int n_in,
                              void* d_out, int out_size, void* d_ws, size_t ws_size,
                              hipStream_t stream) {
    const float* node  = (const float*)d_in[0];
    const int*   group = (const int*)d_in[1];
    const float* W_emb = (const float*)d_in[2];
    const float* b_emb = (const float*)d_in[3];
    const float* w_att = (const float*)d_in[4];
    const float* b_att = (const float*)d_in[5];
    float* out = (float*)d_out;

    float* w = (float*)d_ws;
    float* s_other = w;             // 1024
    float* s_self  = w + 1024;
    float* cmp     = w + 2048;
    float* icsp    = w + 3072;
    float* cmn     = w + 4096;
    float* icsn    = w + 5120;

    kA_scores_stats<<<128, 512, 0, stream>>>(node, group, W_emb, b_emb, w_att,
                                             b_att, s_other, s_self, cmp, icsp,
                                             cmn, icsn);
    kB_out<<<256, 512, 0, stream>>>(node, s_self, s_other, group, b_att,
                                    cmp, icsp, cmn, icsn, out);
}

// Round 8
// 28.626 us; speedup vs baseline: 1.3765x; 1.3765x over previous
//
#include <hip/hip_runtime.h>
#include <hip/hip_bf16.h>

#define NEGC (-1e8f)

__device__ __forceinline__ float lrelu(float x) { return x >= 0.f ? x : 0.2f * x; }

// Shared edge-logit computation. MUST be bit-identical between the stats pass
// (k2) and the output pass (k3): the neg-mask multiplies e by -1e8, so a 1-ulp
// difference becomes ~±50 in the logit and exp() explodes. Add/mul only (no
// fma-contraction ambiguity), fixed association e = ss + soj, with
// soj = s_other[j] + b_att[0] computed identically in both kernels from the
// SAME stored s_other bits.
__device__ __forceinline__ void edge_pq(float ss, float soj, bool same,
                                        float& p, float& q) {
    float e = ss + soj;
    float pin = same ? e : e * NEGC;
    float nin = same ? e * NEGC : e;
    p = lrelu(pin);
    q = lrelu(nin);
}

// ---------------- Kernel 1: scores. 32 blocks x 256 thr; block b owns rows
// [32b, 32b+32) — each node row is read ONCE grid-wide (no lockstep hotspot).
// u1/u2 (128-d each) computed redundantly per block from W_emb (coalesced,
// deterministic -> bit-identical across blocks).
__global__ __launch_bounds__(256) void k1_scores(
        const float* __restrict__ node,
        const float* __restrict__ W_emb,
        const float* __restrict__ b_emb,
        const float* __restrict__ w_att,
        float* __restrict__ s_other_g, float* __restrict__ s_self_g) {
    int t = threadIdx.x;
    int b = blockIdx.x;

    __shared__ float u1[128], u2[128];
    __shared__ float cc[2];

    // u: threads 0..127 -> u1[k], threads 128..255 -> u2[k] (same W reads, L1)
    {
        int k = t & 127;
        const float* wa = w_att + (t >> 7) * 128;
        float a = 0.f;
#pragma unroll 8
        for (int e = 0; e < 128; ++e) a += W_emb[e * 128 + k] * wa[e];
        if (t < 128) u1[k] = a; else u2[k] = a;
    }
    // c1 (wave 0), c2 (wave 1)
    if (t < 64) {
        float c = b_emb[t] * w_att[t] + b_emb[64 + t] * w_att[64 + t];
#pragma unroll
        for (int off = 32; off > 0; off >>= 1) c += __shfl_xor(c, off, 64);
        if (t == 0) cc[0] = c;
    } else if (t < 128) {
        int l = t - 64;
        float c = b_emb[l] * w_att[128 + l] + b_emb[64 + l] * w_att[192 + l];
#pragma unroll
        for (int off = 32; off > 0; off >>= 1) c += __shfl_xor(c, off, 64);
        if (l == 0) cc[1] = c;
    }
    __syncthreads();

    // rows: wave wv handles rows 32b + 8*wv + {0..7}; lane holds float2 of the
    // row (coalesced 512B per row) and a register-resident u fragment.
    int wv = t >> 6, lane = t & 63;
    float2 v1 = ((const float2*)u1)[lane];
    float2 v2 = ((const float2*)u2)[lane];
    float c1 = cc[0], c2 = cc[1];
#pragma unroll
    for (int r = 0; r < 8; ++r) {
        int row = b * 32 + wv * 8 + r;
        float2 x = ((const float2*)(node + (size_t)row * 128))[lane];
        float d1 = x.x * v1.x + x.y * v1.y;
        float d2 = x.x * v2.x + x.y * v2.y;
#pragma unroll
        for (int off = 32; off > 0; off >>= 1) {
            d1 += __shfl_xor(d1, off, 64);
            d2 += __shfl_xor(d2, off, 64);
        }
        if (lane == 0) {
            s_other_g[row] = d1 + c1;
            s_self_g[row]  = d2 + c2;
        }
    }
}

// ---------------- Kernel 2: per-column softmax stats (R4-proven). One wave
// per column, 4 columns/block, register logits, shfl butterflies.
__global__ __launch_bounds__(256) void k2_col_stats(
        const float* __restrict__ s_self,
        const float* __restrict__ s_other,
        const int* __restrict__ group,
        const float* __restrict__ b_att,
        float* __restrict__ cmp, float* __restrict__ icsp,
        float* __restrict__ cmn, float* __restrict__ icsn) {
    int j = blockIdx.x * 4 + (threadIdx.x >> 6);
    int lane = threadIdx.x & 63;
    float soj = s_other[j] + b_att[0];   // the one fixed association
    int gj = group[j];

    float pv[16], nv[16];
    float pmax = -3.4e38f, nmax = -3.4e38f;
#pragma unroll
    for (int k = 0; k < 16; ++k) {
        int i = lane + k * 64;
        float p, q;
        edge_pq(s_self[i], soj, group[i] == gj, p, q);
        pv[k] = p; nv[k] = q;
        pmax = fmaxf(pmax, p);
        nmax = fmaxf(nmax, q);
    }
#pragma unroll
    for (int off = 32; off > 0; off >>= 1) {
        pmax = fmaxf(pmax, __shfl_xor(pmax, off, 64));
        nmax = fmaxf(nmax, __shfl_xor(nmax, off, 64));
    }
    float ps = 0.f, ns = 0.f;
#pragma unroll
    for (int k = 0; k < 16; ++k) {
        ps += __expf(pv[k] - pmax);
        ns += __expf(nv[k] - nmax);
    }
#pragma unroll
    for (int off = 32; off > 0; off >>= 1) {
        ps += __shfl_xor(ps, off, 64);
        ns += __shfl_xor(ns, off, 64);
    }
    if (lane == 0) {
        cmp[j] = pmax; icsp[j] = 1.f / ps;
        cmn[j] = nmax; icsn[j] = 1.f / ns;
    }
}

// ---------------- Kernel 3: out[i,:] = sum_j A[i,j] * relu(node[j,:])
// BI=8 rows/block -> 128 blocks x 512 thr (halves grid-wide node re-reads vs
// BI=4). A tile in LDS as bufT[j][r] (float4 pairs). The j-sweep is ROTATED
// per block (j = ((jj + b) & 63)*16 + g) so blocks touch different rows at any
// instant -> spreads requests across all L2 channels instead of lockstep
// hammering ~16 hot rows (the R7 lesson).
#define BI3 8
__global__ __launch_bounds__(512) void k3_out(
        const float* __restrict__ node,
        const float* __restrict__ s_self,
        const float* __restrict__ s_other,
        const int* __restrict__ group,
        const float* __restrict__ b_att,
        const float* __restrict__ cmp, const float* __restrict__ icsp,
        const float* __restrict__ cmn, const float* __restrict__ icsn,
        float* __restrict__ out) {
    int t = threadIdx.x;       // 0..511
    int b = blockIdx.x;
    int i0 = b * BI3;

    __shared__ float lds[8192];   // 32 KB: A as lds[j*8 + r], then reduce buf
    __shared__ float ss_l[BI3];
    __shared__ int   g_l[BI3];
    if (t < BI3) { ss_l[t] = s_self[i0 + t]; g_l[t] = group[i0 + t]; }
    __syncthreads();

    float ba = b_att[0];
    float ssr[BI3]; int glr[BI3];
#pragma unroll
    for (int r = 0; r < BI3; ++r) { ssr[r] = ss_l[r]; glr[r] = g_l[r]; }

    // A-fill: 8192 entries; each thread 2 j's x 8 rows
#pragma unroll
    for (int e = 0; e < 2; ++e) {
        int j = t + e * 512;
        float soj = s_other[j] + ba;   // identical association to k2
        int gj = group[j];
        float mp = cmp[j], ip = icsp[j], mn = cmn[j], iq = icsn[j];
        float tmp[BI3];
#pragma unroll
        for (int r = 0; r < BI3; ++r) {
            float p, q;
            edge_pq(ssr[r], soj, gj == glr[r], p, q);
            tmp[r] = __expf(p - mp) * ip + __expf(q - mn) * iq;
        }
        *(float4*)&lds[j * 8]     = make_float4(tmp[0], tmp[1], tmp[2], tmp[3]);
        *(float4*)&lds[j * 8 + 4] = make_float4(tmp[4], tmp[5], tmp[6], tmp[7]);
    }
    __syncthreads();

    int g = t >> 5, l32 = t & 31;     // 16 j-groups of 32 lanes
    const float4* nf4 = (const float4*)node;
    float4 acc[BI3];
#pragma unroll
    for (int r = 0; r < BI3; ++r) acc[r] = make_float4(0.f, 0.f, 0.f, 0.f);

    int boff = b & 63;
#pragma unroll 4
    for (int jj = 0; jj < 64; ++jj) {
        int j = (((jj + boff) & 63) << 4) + g;        // rotated sweep
        float4 x = nf4[(size_t)j * 32 + l32];         // coalesced 512B/group
        float4 rn = make_float4(fmaxf(x.x, 0.f), fmaxf(x.y, 0.f),
                                fmaxf(x.z, 0.f), fmaxf(x.w, 0.f));
        float4 a0 = *(const float4*)&lds[j * 8];      // broadcast reads
        float4 a1 = *(const float4*)&lds[j * 8 + 4];
        float aa[BI3] = {a0.x, a0.y, a0.z, a0.w, a1.x, a1.y, a1.z, a1.w};
#pragma unroll
        for (int r = 0; r < BI3; ++r) {
            acc[r].x += aa[r] * rn.x; acc[r].y += aa[r] * rn.y;
            acc[r].z += aa[r] * rn.z; acc[r].w += aa[r] * rn.w;
        }
    }

    // fold the two 32-lane halves of each wave in-register
#pragma unroll
    for (int r = 0; r < BI3; ++r) {
        acc[r].x += __shfl_xor(acc[r].x, 32, 64);
        acc[r].y += __shfl_xor(acc[r].y, 32, 64);
        acc[r].z += __shfl_xor(acc[r].z, 32, 64);
        acc[r].w += __shfl_xor(acc[r].w, 32, 64);
    }

    __syncthreads();  // done reading A; reuse lds as reduce buffer (exactly 32KB)
    if ((t & 32) == 0) {
        int hg = g >> 1;                    // 0..7
        float4* red = (float4*)lds;         // red[hg*256 + r*32 + l32]
#pragma unroll
        for (int r = 0; r < BI3; ++r) red[hg * 256 + r * 32 + l32] = acc[r];
    }
    __syncthreads();

    // 1024 outputs (8 rows x 128 d); 2 per thread, contiguous stores
#pragma unroll
    for (int s = 0; s < 2; ++s) {
        int o = t + s * 512;
        int r = o >> 7, d = o & 127;
        float sum = 0.f;
#pragma unroll
        for (int hg = 0; hg < 8; ++hg) sum += lds[hg * 1024 + r * 128 + d];
        out[(size_t)(i0 + r) * 128 + d] = sum;
    }
}

extern "C" void kernel_launch(void* const* d_in, const int* in_sizes, int n_in,
                              void* d_out, int out_size, void* d_ws, size_t ws_size,
                              hipStream_t stream) {
    const float* node  = (const float*)d_in[0];
    const int*   group = (const int*)d_in[1];
    const float* W_emb = (const float*)d_in[2];
    const float* b_emb = (const float*)d_in[3];
    const float* w_att = (const float*)d_in[4];
    const float* b_att = (const float*)d_in[5];
    float* out = (float*)d_out;

    float* w = (float*)d_ws;
    float* s_other = w;             // 1024
    float* s_self  = w + 1024;
    float* cmp     = w + 2048;
    float* icsp    = w + 3072;
    float* cmn     = w + 4096;
    float* icsn    = w + 5120;

    k1_scores<<<32, 256, 0, stream>>>(node, W_emb, b_emb, w_att,
                                      s_other, s_self);
    k2_col_stats<<<256, 256, 0, stream>>>(s_self, s_other, group, b_att,
                                          cmp, icsp, cmn, icsn);
    k3_out<<<128, 512, 0, stream>>>(node, s_self, s_other, group, b_att,
                                    cmp, icsp, cmn, icsn, out);
}